// Round 15
// baseline (242.020 us; speedup 1.0000x reference)
//
#include <hip/hip_runtime.h>
#include <hip/hip_fp16.h>

#define IN_CH 128
#define HID 64
#define CHUNK1 8192    // edges per p1 block -> 391 blocks (>256 CUs)
#define GBITS 8        // 256 nodes per group
#define SCAN_CHUNK 8192

typedef _Float16 h2 __attribute__((ext_vector_type(2)));
__device__ __forceinline__ h2 asH2(unsigned u) {
    union { unsigned u; h2 h; } x; x.u = u; return x.h;
}
__device__ __forceinline__ unsigned packH2(float a, float b) {
    union { unsigned u; h2 h; } x;
    x.h.x = (_Float16)a; x.h.y = (_Float16)b;
    return x.u;
}

// ---------- p1 count + group-rank: LDS histogram of dst>>8 per edge-chunk ----
// rank8[e] = this edge's rank among its (block,group) peers (atomicAdd return).
// Per-(block,group) count mean ~21 (CHUNK1*256/N), <<255 -> u8 safe.
__global__ __launch_bounds__(512) void k_p1count(const int* __restrict__ dst,
                                                 int* __restrict__ C,
                                                 unsigned char* __restrict__ rank8,
                                                 int E, int G, int NB1) {
    __shared__ int lcnt[512];
    int t = threadIdx.x;
    for (int i = t; i < 512; i += 512) lcnt[i] = 0;
    __syncthreads();
    int lo = blockIdx.x * CHUNK1;
    int hi = min(E, lo + CHUNK1);
    for (int e = lo + t; e < hi; e += 512) {
        int d = __builtin_nontemporal_load(dst + e);
        int r = atomicAdd(&lcnt[d >> GBITS], 1);
        rank8[e] = (unsigned char)r;
    }
    __syncthreads();
    for (int g = t; g < G; g += 512) C[(size_t)g * NB1 + blockIdx.x] = lcnt[g];
}

// ---------- scan pass 1: per-chunk sums ----------
__global__ __launch_bounds__(256) void k_scan_blocksum(const int* __restrict__ a,
                                                       int* __restrict__ bsum, int M) {
    int t = threadIdx.x;
    int base = blockIdx.x * SCAN_CHUNK + t * 32;
    int s = 0;
#pragma unroll
    for (int q = 0; q < 8; ++q) {
        int b = base + q * 4;
        if (b + 3 < M) {
            int4 v = *(const int4*)(a + b);
            s += v.x + v.y + v.z + v.w;
        } else {
            for (int i = 0; i < 4; ++i) if (b + i < M) s += a[b + i];
        }
    }
#pragma unroll
    for (int off = 32; off; off >>= 1) s += __shfl_down(s, off);
    __shared__ int ws[4];
    if ((t & 63) == 0) ws[t >> 6] = s;
    __syncthreads();
    if (t == 0) bsum[blockIdx.x] = ws[0] + ws[1] + ws[2] + ws[3];
}

// ---------- scan pass 2 (fused bsums-scan + apply, in place) ----------
// Each block redundantly sums bsum[0..blockIdx) in one wave (nbs<=64).
__global__ __launch_bounds__(256) void k_scan_apply(int* __restrict__ a,
                                                    const int* __restrict__ bsum,
                                                    int nbs, int M, int E) {
    __shared__ int sboff;
    int t = threadIdx.x;
    if (t < 64) {
        int v = (t < nbs && t < (int)blockIdx.x) ? bsum[t] : 0;
#pragma unroll
        for (int off = 32; off; off >>= 1) v += __shfl_xor(v, off);
        if (t == 0) sboff = v;
    }
    int base = blockIdx.x * SCAN_CHUNK + t * 32;
    int v[32];
    int tsum = 0;
#pragma unroll
    for (int q = 0; q < 8; ++q) {
        int b = base + q * 4;
        if (b + 3 < M) {
            int4 w = *(const int4*)(a + b);
            v[q * 4 + 0] = w.x; v[q * 4 + 1] = w.y; v[q * 4 + 2] = w.z; v[q * 4 + 3] = w.w;
        } else {
            for (int i = 0; i < 4; ++i) v[q * 4 + i] = (b + i < M) ? a[b + i] : 0;
        }
        tsum += v[q * 4] + v[q * 4 + 1] + v[q * 4 + 2] + v[q * 4 + 3];
    }
    __shared__ int sh[256];
    sh[t] = tsum;
    __syncthreads();
    for (int off = 1; off < 256; off <<= 1) {
        int u = (t >= off) ? sh[t - off] : 0;
        __syncthreads();
        sh[t] += u;
        __syncthreads();
    }
    int run = ((t == 0) ? 0 : sh[t - 1]) + sboff;
#pragma unroll
    for (int q = 0; q < 8; ++q) {
        int b = base + q * 4;
        int o0 = run;            run += v[q * 4 + 0];
        int o1 = run;            run += v[q * 4 + 1];
        int o2 = run;            run += v[q * 4 + 2];
        int o3 = run;            run += v[q * 4 + 3];
        if (b + 3 < M) { *(int4*)(a + b) = make_int4(o0, o1, o2, o3); }
        else {
            if (b     < M) a[b]     = o0;
            if (b + 1 < M) a[b + 1] = o1;
            if (b + 2 < M) a[b + 2] = o2;
            if (b + 3 < M) a[b + 3] = o3;
        }
    }
    if (blockIdx.x == 0 && t == 0) a[M] = E;
}

// ---------- p1 scatter: pure streaming, no LDS (rank trick) ----------
__global__ __launch_bounds__(512) void k_p1scat(const int* __restrict__ src,
                                                const int* __restrict__ dst,
                                                const unsigned char* __restrict__ rank8,
                                                const int* __restrict__ S,
                                                unsigned int* __restrict__ part,
                                                int E, int NB1) {
    const int blk = blockIdx.x;
    const int t = threadIdx.x;
    int lo = blk * CHUNK1;
    int hi = min(E, lo + CHUNK1);
    for (int e = lo + t; e < hi; e += 512) {
        int d = __builtin_nontemporal_load(dst + e);
        int s = __builtin_nontemporal_load(src + e);
        int r = rank8[e];
        int pos = S[(size_t)(d >> GBITS) * NB1 + blk] + r;
        part[pos] = ((unsigned)s << GBITS) | (unsigned)(d & ((1 << GBITS) - 1));
    }
}

// ---------- p2: single-pass per-group CSR build (register-staged rank trick) ----
__global__ __launch_bounds__(512) void k_p2(const unsigned int* __restrict__ part,
                                            const int* __restrict__ S,
                                            int* __restrict__ rowptr,
                                            float* __restrict__ dinv,
                                            int* __restrict__ esorted,
                                            int E, int N, int G, int NB1) {
    __shared__ int lcnt[256], lpre[256], lexc[256];
    int t = threadIdx.x;
    int g = blockIdx.x;
    int base = S[(size_t)g * NB1];
    int end  = (g == G - 1) ? E : S[(size_t)(g + 1) * NB1];
    if (t < 256) lcnt[t] = 0;
    __syncthreads();
    unsigned int  ed[18];
    unsigned char rk[18];
#pragma unroll
    for (int q = 0; q < 18; ++q) {
        int i = base + t + q * 512;
        if (i < end) {
            unsigned p = part[i];
            ed[q] = p;
            rk[q] = (unsigned char)atomicAdd(&lcnt[p & 255], 1);  // deg<256 always
        }
    }
    __syncthreads();
    int v = 0;
    if (t < 256) { v = lcnt[t]; lpre[t] = v; }
    __syncthreads();
    for (int off = 1; off < 256; off <<= 1) {
        int u = (t >= off && t < 256) ? lpre[t - off] : 0;
        __syncthreads();
        if (t < 256) lpre[t] += u;
        __syncthreads();
    }
    if (t < 256) {
        int excl = lpre[t] - v;
        lexc[t] = excl;
        int node = (g << GBITS) + t;
        if (node < N) {
            rowptr[node] = base + excl;
            dinv[node] = rsqrtf(1.0f + (float)v);
        }
    }
    if (g == 0 && t == 0) rowptr[N] = E;
    __syncthreads();
#pragma unroll
    for (int q = 0; q < 18; ++q) {
        int i = base + t + q * 512;
        if (i < end) {
            unsigned p = ed[q];
            esorted[base + lexc[p & 255] + (int)rk[q]] = (int)(p >> GBITS);
        }
    }
}

// -------- layer 1 GEMM via v_dot2_f32_f16 (R13-proven) --------
__global__ __launch_bounds__(256) void k_gemm1(const float* __restrict__ x,
                                               const float* __restrict__ W1,
                                               const float* __restrict__ dinv,
                                               __half* __restrict__ hp1h, int N) {
    __shared__ unsigned sW[64 * 64];   // [j2][k] packed, 16KB
    __shared__ unsigned sx[16 * 64];   // [n][j2] packed,  4KB
    const int tid = threadIdx.x;
    const int node0 = blockIdx.x * 16;

#pragma unroll
    for (int q = 0; q < 16; ++q) {
        int idx = tid + q * 256;
        int j2 = idx >> 6, k = idx & 63;
        sW[idx] = packH2(W1[(2 * j2) * HID + k], W1[(2 * j2 + 1) * HID + k]);
    }
#pragma unroll
    for (int q = 0; q < 4; ++q) {
        int idx = tid + q * 256;
        int n = idx >> 6, j2 = idx & 63;
        float2 v = *(const float2*)(x + (size_t)(node0 + n) * IN_CH + 2 * j2);
        sx[idx] = packH2(v.x, v.y);
    }
    __syncthreads();

    const int k  = tid & 63;
    const int n0 = tid >> 6;  // 0..3
    float a0 = 0.f, a1 = 0.f, a2 = 0.f, a3 = 0.f;
#pragma unroll 8
    for (int j2 = 0; j2 < 64; ++j2) {
        h2 w = asH2(sW[j2 * 64 + k]);
        a0 = __builtin_amdgcn_fdot2(asH2(sx[(n0     ) * 64 + j2]), w, a0, false);
        a1 = __builtin_amdgcn_fdot2(asH2(sx[(n0 +  4) * 64 + j2]), w, a1, false);
        a2 = __builtin_amdgcn_fdot2(asH2(sx[(n0 +  8) * 64 + j2]), w, a2, false);
        a3 = __builtin_amdgcn_fdot2(asH2(sx[(n0 + 12) * 64 + j2]), w, a3, false);
    }
    hp1h[(size_t)(node0 + n0     ) * HID + k] = __float2half(a0 * dinv[node0 + n0]);
    hp1h[(size_t)(node0 + n0 +  4) * HID + k] = __float2half(a1 * dinv[node0 + n0 + 4]);
    hp1h[(size_t)(node0 + n0 +  8) * HID + k] = __float2half(a2 * dinv[node0 + n0 + 8]);
    hp1h[(size_t)(node0 + n0 + 12) * HID + k] = __float2half(a3 * dinv[node0 + n0 + 12]);
}

// ---- layer 1 aggregate + relu + bias + layer 2 projection, fused (R10 form) ----
__global__ __launch_bounds__(256) void k_agg1(const int* __restrict__ rowptr,
                                              const int* __restrict__ esorted,
                                              const __half2* __restrict__ hp1h,
                                              const float* __restrict__ dinv,
                                              const float* __restrict__ b1,
                                              const float* __restrict__ W2,
                                              float* __restrict__ hp2, int N) {
    int wid = (blockIdx.x * blockDim.x + threadIdx.x) >> 6;
    if (wid >= N) return;
    const int lane = threadIdx.x & 63;
    const int k32  = lane & 31;
    const int half = lane >> 5;
    int beg = rowptr[wid], end = rowptr[wid + 1];

    float ax = 0.f, ay = 0.f;
    int e = beg;
    for (; e + 15 < end; e += 16) {
        const int* ep = esorted + e + 8 * half;    // this half-wave's 8 edges
        int s0 = ep[0], s1 = ep[1], s2 = ep[2], s3 = ep[3];
        int s4 = ep[4], s5 = ep[5], s6 = ep[6], s7 = ep[7];
        __half2 h0 = hp1h[(unsigned)(s0 * 32 + k32)];
        __half2 h1 = hp1h[(unsigned)(s1 * 32 + k32)];
        __half2 h2 = hp1h[(unsigned)(s2 * 32 + k32)];
        __half2 h3 = hp1h[(unsigned)(s3 * 32 + k32)];
        h0 = __hadd2(h0, hp1h[(unsigned)(s4 * 32 + k32)]);
        h1 = __hadd2(h1, hp1h[(unsigned)(s5 * 32 + k32)]);
        h2 = __hadd2(h2, hp1h[(unsigned)(s6 * 32 + k32)]);
        h3 = __hadd2(h3, hp1h[(unsigned)(s7 * 32 + k32)]);
        float2 f0 = __half22float2(__hadd2(h0, h1));
        float2 f1 = __half22float2(__hadd2(h2, h3));
        ax += f0.x + f1.x;
        ay += f0.y + f1.y;
    }
    for (; e + 1 < end; e += 2) {                  // pairs: half-wave h takes e+h
        int s = esorted[e + half];
        float2 f = __half22float2(hp1h[(unsigned)(s * 32 + k32)]);
        ax += f.x;
        ay += f.y;
    }
    if (e < end) {                                 // odd final edge: half 0 only
        int s = esorted[e];
        float2 f = __half22float2(hp1h[(unsigned)(s * 32 + k32)]);
        if (half == 0) { ax += f.x; ay += f.y; }
    }
    ax += __shfl_xor(ax, 32);                      // combine half-wave edge sets
    ay += __shfl_xor(ay, 32);

    float2 fs = __half22float2(hp1h[(unsigned)(wid * 32 + k32)]);  // self-loop
    ax += fs.x;
    ay += fs.y;

    float dj = dinv[wid];
    float2 bb = *(const float2*)(b1 + 2 * k32);
    float h0 = fmaxf(fmaf(dj, ax, bb.x), 0.0f);
    float h1 = fmaxf(fmaf(dj, ay, bb.y), 0.0f);
    float4 w4 = *(const float4*)(W2 + 4 * k32);
    float p0 = h0 * w4.x + h1 * w4.z;
    float p1 = h0 * w4.y + h1 * w4.w;
#pragma unroll
    for (int off = 32; off; off >>= 1) {
        p0 += __shfl_xor(p0, off);
        p1 += __shfl_xor(p1, off);
    }
    if (lane == 0) {   // halves are duplicates after the xor-32 combine -> x0.5
        hp2[(size_t)wid * 2 + 0] = p0 * 0.5f * dj;
        hp2[(size_t)wid * 2 + 1] = p1 * 0.5f * dj;
    }
}

// ---------------- layer 2 aggregate + epilogue ----------------
__global__ __launch_bounds__(256) void k_agg2(const int* __restrict__ rowptr,
                                              const int* __restrict__ esorted,
                                              const float* __restrict__ hp2,
                                              const float* __restrict__ dinv,
                                              const float* __restrict__ b2,
                                              float* __restrict__ out, int N) {
    int gid = blockIdx.x * blockDim.x + threadIdx.x;
    int j = gid >> 3;
    if (j >= N) return;
    int l = gid & 7;
    int beg = rowptr[j], end = rowptr[j + 1];
    float ax = 0.f, ay = 0.f;
    for (int e = beg + l; e < end; e += 8) {
        int s = esorted[e];
        float2 v = *(const float2*)(hp2 + (size_t)s * 2);
        ax += v.x;
        ay += v.y;
    }
#pragma unroll
    for (int off = 1; off < 8; off <<= 1) {
        ax += __shfl_xor(ax, off);
        ay += __shfl_xor(ay, off);
    }
    if (l == 0) {
        float2 self = *(const float2*)(hp2 + (size_t)j * 2);
        float dj = dinv[j];
        out[(size_t)j * 2 + 0] = fmaf(dj, ax + self.x, b2[0]);
        out[(size_t)j * 2 + 1] = fmaf(dj, ay + self.y, b2[1]);
    }
}

extern "C" void kernel_launch(void* const* d_in, const int* in_sizes, int n_in,
                              void* d_out, int out_size, void* d_ws, size_t ws_size,
                              hipStream_t stream) {
    const float* x  = (const float*)d_in[0];
    const int*   ei = (const int*)d_in[1];
    const float* W1 = (const float*)d_in[2];
    const float* b1 = (const float*)d_in[3];
    const float* W2 = (const float*)d_in[4];
    const float* b2 = (const float*)d_in[5];
    float* out = (float*)d_out;

    const int N = in_sizes[0] / IN_CH;   // 100000
    const int E = in_sizes[1] / 2;       // 3200000
    const int* src = ei;
    const int* dst = ei + E;

    const int G   = (N + 255) >> GBITS;             // 391 groups of 256 nodes
    const int NB1 = (E + CHUNK1 - 1) / CHUNK1;      // 391 p1 blocks
    const int M   = G * NB1;                        // 152881 counts
    const int NBs = (M + SCAN_CHUNK - 1) / SCAN_CHUNK;  // 19 (<=64 required)

    char* ws = (char*)d_ws;
    size_t o = 0;
    auto carve = [&](size_t bytes) -> char* {
        char* p = ws + o;
        o = (o + bytes + 255) & ~(size_t)255;
        return p;
    };
    int*           S       = (int*)carve(((size_t)M + 1) * 4);       // counts -> scanned
    unsigned char* rank8   = (unsigned char*)carve((size_t)E);       // 3.2 MB
    unsigned int*  part    = (unsigned int*)carve((size_t)E * 4);    // 12.8 MB
    int*           rowptr  = (int*)carve(((size_t)N + 1) * 4);
    float*         dinv    = (float*)carve((size_t)N * 4);
    int*           bsum    = (int*)carve(128 * 4);
    int*           esorted = (int*)carve((size_t)E * 4);             // 12.8 MB
    __half*        hp1h    = (__half*)carve((size_t)N * HID * 2);    // 12.8 MB fp16
    float*         hp2     = (float*)carve((size_t)N * 2 * 4);
    (void)ws_size;

    k_p1count<<<NB1, 512, 0, stream>>>(dst, S, rank8, E, G, NB1);
    k_scan_blocksum<<<NBs, 256, 0, stream>>>(S, bsum, M);
    k_scan_apply<<<NBs, 256, 0, stream>>>(S, bsum, NBs, M, E);
    k_p1scat<<<NB1, 512, 0, stream>>>(src, dst, rank8, S, part, E, NB1);
    k_p2<<<G, 512, 0, stream>>>(part, S, rowptr, dinv, esorted, E, N, G, NB1);

    k_gemm1<<<(N + 15) / 16, 256, 0, stream>>>(x, W1, dinv, hp1h, N);
    k_agg1<<<(unsigned)(((size_t)N * 64 + 255) / 256), 256, 0, stream>>>(
        rowptr, esorted, (const __half2*)hp1h, dinv, b1, W2, hp2, N);
    k_agg2<<<(unsigned)(((size_t)N * 8 + 255) / 256), 256, 0, stream>>>(
        rowptr, esorted, hp2, dinv, b2, out, N);
}

// Round 16
// 209.524 us; speedup vs baseline: 1.1551x; 1.1551x over previous
//
#include <hip/hip_runtime.h>
#include <hip/hip_fp16.h>

#define IN_CH 128
#define HID 64
#define CHUNK1 16384   // edges per p1 block (R10/R13-proven; 8192 regressed twice)
#define GBITS 8        // 256 nodes per group
#define SCAN_CHUNK 8192

typedef _Float16 h2 __attribute__((ext_vector_type(2)));
__device__ __forceinline__ h2 asH2(unsigned u) {
    union { unsigned u; h2 h; } x; x.u = u; return x.h;
}
__device__ __forceinline__ unsigned packH2(float a, float b) {
    union { unsigned u; h2 h; } x;
    x.h.x = (_Float16)a; x.h.y = (_Float16)b;
    return x.u;
}

// ---------- p1 count: LDS histogram of dst>>8 per edge-chunk ----------
__global__ __launch_bounds__(512) void k_p1count(const int* __restrict__ dst,
                                                 int* __restrict__ C,
                                                 int E, int G, int NB1) {
    __shared__ int lcnt[512];
    int t = threadIdx.x;
    for (int i = t; i < G; i += 512) lcnt[i] = 0;
    __syncthreads();
    int lo = blockIdx.x * CHUNK1;
    int hi = min(E, lo + CHUNK1);
    for (int e = lo + t; e < hi; e += 512) {
        int d = __builtin_nontemporal_load(dst + e);
        atomicAdd(&lcnt[d >> GBITS], 1);
    }
    __syncthreads();
    for (int g = t; g < G; g += 512) C[(size_t)g * NB1 + blockIdx.x] = lcnt[g];
}

// ---------- multi-block exclusive scan, in place (R5-verified) ----------
__global__ __launch_bounds__(256) void k_scan_blocksum(const int* __restrict__ a,
                                                       int* __restrict__ bsum, int M) {
    int t = threadIdx.x;
    int base = blockIdx.x * SCAN_CHUNK + t * 32;
    int s = 0;
#pragma unroll
    for (int q = 0; q < 8; ++q) {
        int b = base + q * 4;
        if (b + 3 < M) {
            int4 v = *(const int4*)(a + b);
            s += v.x + v.y + v.z + v.w;
        } else {
            for (int i = 0; i < 4; ++i) if (b + i < M) s += a[b + i];
        }
    }
#pragma unroll
    for (int off = 32; off; off >>= 1) s += __shfl_down(s, off);
    __shared__ int ws[4];
    if ((t & 63) == 0) ws[t >> 6] = s;
    __syncthreads();
    if (t == 0) bsum[blockIdx.x] = ws[0] + ws[1] + ws[2] + ws[3];
}

__global__ __launch_bounds__(128) void k_scan_bsums(int* __restrict__ bsum, int nb) {
    __shared__ int sh[128];
    int t = threadIdx.x;
    int v = (t < nb) ? bsum[t] : 0;
    sh[t] = v;
    __syncthreads();
    for (int off = 1; off < 128; off <<= 1) {
        int u = (t >= off) ? sh[t - off] : 0;
        __syncthreads();
        sh[t] += u;
        __syncthreads();
    }
    if (t < nb) bsum[t] = (t == 0) ? 0 : sh[t - 1];
}

__global__ __launch_bounds__(256) void k_scan_apply(int* __restrict__ a,
                                                    const int* __restrict__ boff,
                                                    int M, int E) {
    int t = threadIdx.x;
    int base = blockIdx.x * SCAN_CHUNK + t * 32;
    int v[32];
    int tsum = 0;
#pragma unroll
    for (int q = 0; q < 8; ++q) {
        int b = base + q * 4;
        if (b + 3 < M) {
            int4 w = *(const int4*)(a + b);
            v[q * 4 + 0] = w.x; v[q * 4 + 1] = w.y; v[q * 4 + 2] = w.z; v[q * 4 + 3] = w.w;
        } else {
            for (int i = 0; i < 4; ++i) v[q * 4 + i] = (b + i < M) ? a[b + i] : 0;
        }
        tsum += v[q * 4] + v[q * 4 + 1] + v[q * 4 + 2] + v[q * 4 + 3];
    }
    __shared__ int sh[256];
    sh[t] = tsum;
    __syncthreads();
    for (int off = 1; off < 256; off <<= 1) {
        int u = (t >= off) ? sh[t - off] : 0;
        __syncthreads();
        sh[t] += u;
        __syncthreads();
    }
    int run = ((t == 0) ? 0 : sh[t - 1]) + boff[blockIdx.x];
#pragma unroll
    for (int q = 0; q < 8; ++q) {
        int b = base + q * 4;
        int o0 = run;            run += v[q * 4 + 0];
        int o1 = run;            run += v[q * 4 + 1];
        int o2 = run;            run += v[q * 4 + 2];
        int o3 = run;            run += v[q * 4 + 3];
        if (b + 3 < M) { *(int4*)(a + b) = make_int4(o0, o1, o2, o3); }
        else {
            if (b     < M) a[b]     = o0;
            if (b + 1 < M) a[b + 1] = o1;
            if (b + 2 < M) a[b + 2] = o2;
            if (b + 3 < M) a[b + 3] = o3;
        }
    }
    if (blockIdx.x == 0 && t == 0) a[M] = E;
}

// ---------- p1 scatter: edges -> group-contiguous part[], LDS cursors ----------
__global__ __launch_bounds__(512) void k_p1scat(const int* __restrict__ src,
                                                const int* __restrict__ dst,
                                                const int* __restrict__ S,
                                                unsigned int* __restrict__ part,
                                                int E, int G, int NB1) {
    __shared__ int lcur[512];
    int t = threadIdx.x;
    for (int g = t; g < G; g += 512) lcur[g] = S[(size_t)g * NB1 + blockIdx.x];
    __syncthreads();
    int lo = blockIdx.x * CHUNK1;
    int hi = min(E, lo + CHUNK1);
    for (int e = lo + t; e < hi; e += 512) {
        int d = __builtin_nontemporal_load(dst + e);
        int s = __builtin_nontemporal_load(src + e);
        int pos = atomicAdd(&lcur[d >> GBITS], 1);
        part[pos] = ((unsigned)s << GBITS) | (unsigned)(d & ((1 << GBITS) - 1));
    }
}

// ---------- p2: single-pass per-group CSR build (register-staged rank trick) ----
__global__ __launch_bounds__(512) void k_p2(const unsigned int* __restrict__ part,
                                            const int* __restrict__ S,
                                            int* __restrict__ rowptr,
                                            float* __restrict__ dinv,
                                            int* __restrict__ esorted,
                                            int E, int N, int G, int NB1) {
    __shared__ int lcnt[256], lpre[256], lexc[256];
    int t = threadIdx.x;
    int g = blockIdx.x;
    int base = S[(size_t)g * NB1];
    int end  = (g == G - 1) ? E : S[(size_t)(g + 1) * NB1];
    if (t < 256) lcnt[t] = 0;
    __syncthreads();
    unsigned int  ed[18];
    unsigned char rk[18];
#pragma unroll
    for (int q = 0; q < 18; ++q) {
        int i = base + t + q * 512;
        if (i < end) {
            unsigned p = part[i];
            ed[q] = p;
            rk[q] = (unsigned char)atomicAdd(&lcnt[p & 255], 1);  // deg<256 always
        }
    }
    __syncthreads();
    int v = 0;
    if (t < 256) { v = lcnt[t]; lpre[t] = v; }
    __syncthreads();
    for (int off = 1; off < 256; off <<= 1) {
        int u = (t >= off && t < 256) ? lpre[t - off] : 0;
        __syncthreads();
        if (t < 256) lpre[t] += u;
        __syncthreads();
    }
    if (t < 256) {
        int excl = lpre[t] - v;
        lexc[t] = excl;
        int node = (g << GBITS) + t;
        if (node < N) {
            rowptr[node] = base + excl;
            dinv[node] = rsqrtf(1.0f + (float)v);
        }
    }
    if (g == 0 && t == 0) rowptr[N] = E;
    __syncthreads();
#pragma unroll
    for (int q = 0; q < 18; ++q) {
        int i = base + t + q * 512;
        if (i < end) {
            unsigned p = ed[q];
            esorted[base + lexc[p & 255] + (int)rk[q]] = (int)(p >> GBITS);
        }
    }
}

// -------- layer 1 GEMM via v_dot2_f32_f16: hp1h = fp16( dinv * (x @ W1) ) ----
__global__ __launch_bounds__(256) void k_gemm1(const float* __restrict__ x,
                                               const float* __restrict__ W1,
                                               const float* __restrict__ dinv,
                                               __half* __restrict__ hp1h, int N) {
    __shared__ unsigned sW[64 * 64];   // [j2][k] packed, 16KB
    __shared__ unsigned sx[16 * 64];   // [n][j2] packed,  4KB
    const int tid = threadIdx.x;
    const int node0 = blockIdx.x * 16;

#pragma unroll
    for (int q = 0; q < 16; ++q) {
        int idx = tid + q * 256;
        int j2 = idx >> 6, k = idx & 63;
        sW[idx] = packH2(W1[(2 * j2) * HID + k], W1[(2 * j2 + 1) * HID + k]);
    }
#pragma unroll
    for (int q = 0; q < 4; ++q) {
        int idx = tid + q * 256;
        int n = idx >> 6, j2 = idx & 63;
        float2 v = *(const float2*)(x + (size_t)(node0 + n) * IN_CH + 2 * j2);
        sx[idx] = packH2(v.x, v.y);
    }
    __syncthreads();

    const int k  = tid & 63;
    const int n0 = tid >> 6;  // 0..3
    float a0 = 0.f, a1 = 0.f, a2 = 0.f, a3 = 0.f;
#pragma unroll 8
    for (int j2 = 0; j2 < 64; ++j2) {
        h2 w = asH2(sW[j2 * 64 + k]);
        a0 = __builtin_amdgcn_fdot2(asH2(sx[(n0     ) * 64 + j2]), w, a0, false);
        a1 = __builtin_amdgcn_fdot2(asH2(sx[(n0 +  4) * 64 + j2]), w, a1, false);
        a2 = __builtin_amdgcn_fdot2(asH2(sx[(n0 +  8) * 64 + j2]), w, a2, false);
        a3 = __builtin_amdgcn_fdot2(asH2(sx[(n0 + 12) * 64 + j2]), w, a3, false);
    }
    hp1h[(size_t)(node0 + n0     ) * HID + k] = __float2half(a0 * dinv[node0 + n0]);
    hp1h[(size_t)(node0 + n0 +  4) * HID + k] = __float2half(a1 * dinv[node0 + n0 + 4]);
    hp1h[(size_t)(node0 + n0 +  8) * HID + k] = __float2half(a2 * dinv[node0 + n0 + 8]);
    hp1h[(size_t)(node0 + n0 + 12) * HID + k] = __float2half(a3 * dinv[node0 + n0 + 12]);
}

// ---- layer 1 aggregate + relu + bias + layer 2 projection, fused (R10 form) ----
__global__ __launch_bounds__(256) void k_agg1(const int* __restrict__ rowptr,
                                              const int* __restrict__ esorted,
                                              const __half2* __restrict__ hp1h,
                                              const float* __restrict__ dinv,
                                              const float* __restrict__ b1,
                                              const float* __restrict__ W2,
                                              float* __restrict__ hp2, int N) {
    int wid = (blockIdx.x * blockDim.x + threadIdx.x) >> 6;
    if (wid >= N) return;
    const int lane = threadIdx.x & 63;
    const int k32  = lane & 31;
    const int half = lane >> 5;
    int beg = rowptr[wid], end = rowptr[wid + 1];

    float ax = 0.f, ay = 0.f;
    int e = beg;
    for (; e + 31 < end; e += 32) {
        const int* ep = esorted + e + 16 * half;   // this half-wave's 16 edges
        int s0 = ep[0],  s1 = ep[1],  s2 = ep[2],  s3 = ep[3];
        int s4 = ep[4],  s5 = ep[5],  s6 = ep[6],  s7 = ep[7];
        int s8 = ep[8],  s9 = ep[9],  sa = ep[10], sb = ep[11];
        int sc = ep[12], sd = ep[13], se = ep[14], sf = ep[15];
        __half2 g0 = hp1h[(unsigned)(s0 * 32 + k32)];
        __half2 g1 = hp1h[(unsigned)(s1 * 32 + k32)];
        __half2 g2 = hp1h[(unsigned)(s2 * 32 + k32)];
        __half2 g3 = hp1h[(unsigned)(s3 * 32 + k32)];
        __half2 g4 = hp1h[(unsigned)(s4 * 32 + k32)];
        __half2 g5 = hp1h[(unsigned)(s5 * 32 + k32)];
        __half2 g6 = hp1h[(unsigned)(s6 * 32 + k32)];
        __half2 g7 = hp1h[(unsigned)(s7 * 32 + k32)];
        __half2 g8 = hp1h[(unsigned)(s8 * 32 + k32)];
        __half2 g9 = hp1h[(unsigned)(s9 * 32 + k32)];
        __half2 ga = hp1h[(unsigned)(sa * 32 + k32)];
        __half2 gb = hp1h[(unsigned)(sb * 32 + k32)];
        __half2 gc = hp1h[(unsigned)(sc * 32 + k32)];
        __half2 gd = hp1h[(unsigned)(sd * 32 + k32)];
        __half2 ge = hp1h[(unsigned)(se * 32 + k32)];
        __half2 gf = hp1h[(unsigned)(sf * 32 + k32)];
        __half2 h0 = __hadd2(g0, g4), h1 = __hadd2(g1, g5);
        __half2 h2 = __hadd2(g2, g6), h3 = __hadd2(g3, g7);
        float2 f0 = __half22float2(__hadd2(h0, h1));
        float2 f1 = __half22float2(__hadd2(h2, h3));
        __half2 h4 = __hadd2(g8, gc), h5 = __hadd2(g9, gd);
        __half2 h6 = __hadd2(ga, ge), h7 = __hadd2(gb, gf);
        float2 f2 = __half22float2(__hadd2(h4, h5));
        float2 f3 = __half22float2(__hadd2(h6, h7));
        ax += (f0.x + f1.x) + (f2.x + f3.x);
        ay += (f0.y + f1.y) + (f2.y + f3.y);
    }
    for (; e + 15 < end; e += 16) {
        const int* ep = esorted + e + 8 * half;    // this half-wave's 8 edges
        int s0 = ep[0], s1 = ep[1], s2 = ep[2], s3 = ep[3];
        int s4 = ep[4], s5 = ep[5], s6 = ep[6], s7 = ep[7];
        __half2 h0 = hp1h[(unsigned)(s0 * 32 + k32)];
        __half2 h1 = hp1h[(unsigned)(s1 * 32 + k32)];
        __half2 h2 = hp1h[(unsigned)(s2 * 32 + k32)];
        __half2 h3 = hp1h[(unsigned)(s3 * 32 + k32)];
        h0 = __hadd2(h0, hp1h[(unsigned)(s4 * 32 + k32)]);
        h1 = __hadd2(h1, hp1h[(unsigned)(s5 * 32 + k32)]);
        h2 = __hadd2(h2, hp1h[(unsigned)(s6 * 32 + k32)]);
        h3 = __hadd2(h3, hp1h[(unsigned)(s7 * 32 + k32)]);
        float2 f0 = __half22float2(__hadd2(h0, h1));
        float2 f1 = __half22float2(__hadd2(h2, h3));
        ax += f0.x + f1.x;
        ay += f0.y + f1.y;
    }
    for (; e + 1 < end; e += 2) {                  // pairs: half-wave h takes e+h
        int s = esorted[e + half];
        float2 f = __half22float2(hp1h[(unsigned)(s * 32 + k32)]);
        ax += f.x;
        ay += f.y;
    }
    if (e < end) {                                 // odd final edge: half 0 only
        int s = esorted[e];
        float2 f = __half22float2(hp1h[(unsigned)(s * 32 + k32)]);
        if (half == 0) { ax += f.x; ay += f.y; }
    }
    ax += __shfl_xor(ax, 32);                      // combine half-wave edge sets
    ay += __shfl_xor(ay, 32);

    float2 fs = __half22float2(hp1h[(unsigned)(wid * 32 + k32)]);  // self-loop
    ax += fs.x;
    ay += fs.y;

    float dj = dinv[wid];
    float2 bb = *(const float2*)(b1 + 2 * k32);
    float h0 = fmaxf(fmaf(dj, ax, bb.x), 0.0f);
    float h1 = fmaxf(fmaf(dj, ay, bb.y), 0.0f);
    float4 w4 = *(const float4*)(W2 + 4 * k32);
    float p0 = h0 * w4.x + h1 * w4.z;
    float p1 = h0 * w4.y + h1 * w4.w;
#pragma unroll
    for (int off = 32; off; off >>= 1) {
        p0 += __shfl_xor(p0, off);
        p1 += __shfl_xor(p1, off);
    }
    if (lane == 0) {   // halves are duplicates after the xor-32 combine -> x0.5
        hp2[(size_t)wid * 2 + 0] = p0 * 0.5f * dj;
        hp2[(size_t)wid * 2 + 1] = p1 * 0.5f * dj;
    }
}

// ---------------- layer 2 aggregate + epilogue ----------------
__global__ __launch_bounds__(256) void k_agg2(const int* __restrict__ rowptr,
                                              const int* __restrict__ esorted,
                                              const float* __restrict__ hp2,
                                              const float* __restrict__ dinv,
                                              const float* __restrict__ b2,
                                              float* __restrict__ out, int N) {
    int gid = blockIdx.x * blockDim.x + threadIdx.x;
    int j = gid >> 3;
    if (j >= N) return;
    int l = gid & 7;
    int beg = rowptr[j], end = rowptr[j + 1];
    float ax = 0.f, ay = 0.f;
    for (int e = beg + l; e < end; e += 8) {
        int s = esorted[e];
        float2 v = *(const float2*)(hp2 + (size_t)s * 2);
        ax += v.x;
        ay += v.y;
    }
#pragma unroll
    for (int off = 1; off < 8; off <<= 1) {
        ax += __shfl_xor(ax, off);
        ay += __shfl_xor(ay, off);
    }
    if (l == 0) {
        float2 self = *(const float2*)(hp2 + (size_t)j * 2);
        float dj = dinv[j];
        out[(size_t)j * 2 + 0] = fmaf(dj, ax + self.x, b2[0]);
        out[(size_t)j * 2 + 1] = fmaf(dj, ay + self.y, b2[1]);
    }
}

extern "C" void kernel_launch(void* const* d_in, const int* in_sizes, int n_in,
                              void* d_out, int out_size, void* d_ws, size_t ws_size,
                              hipStream_t stream) {
    const float* x  = (const float*)d_in[0];
    const int*   ei = (const int*)d_in[1];
    const float* W1 = (const float*)d_in[2];
    const float* b1 = (const float*)d_in[3];
    const float* W2 = (const float*)d_in[4];
    const float* b2 = (const float*)d_in[5];
    float* out = (float*)d_out;

    const int N = in_sizes[0] / IN_CH;   // 100000
    const int E = in_sizes[1] / 2;       // 3200000
    const int* src = ei;
    const int* dst = ei + E;

    const int G   = (N + 255) >> GBITS;             // 391 groups of 256 nodes
    const int NB1 = (E + CHUNK1 - 1) / CHUNK1;      // 196 p1 blocks
    const int M   = G * NB1;                        // 76636 counts
    const int NBs = (M + SCAN_CHUNK - 1) / SCAN_CHUNK;  // 10 (<=128 required)

    char* ws = (char*)d_ws;
    size_t o = 0;
    auto carve = [&](size_t bytes) -> char* {
        char* p = ws + o;
        o = (o + bytes + 255) & ~(size_t)255;
        return p;
    };
    int*          S       = (int*)carve(((size_t)M + 1) * 4);       // counts -> scanned
    unsigned int* part    = (unsigned int*)carve((size_t)E * 4);    // 12.8 MB
    int*          rowptr  = (int*)carve(((size_t)N + 1) * 4);
    float*        dinv    = (float*)carve((size_t)N * 4);
    int*          bsum    = (int*)carve(128 * 4);
    int*          esorted = (int*)carve((size_t)E * 4);             // 12.8 MB
    __half*       hp1h    = (__half*)carve((size_t)N * HID * 2);    // 12.8 MB fp16
    float*        hp2     = (float*)carve((size_t)N * 2 * 4);
    (void)ws_size;

    k_p1count<<<NB1, 512, 0, stream>>>(dst, S, E, G, NB1);
    k_scan_blocksum<<<NBs, 256, 0, stream>>>(S, bsum, M);
    k_scan_bsums<<<1, 128, 0, stream>>>(bsum, NBs);
    k_scan_apply<<<NBs, 256, 0, stream>>>(S, bsum, M, E);
    k_p1scat<<<NB1, 512, 0, stream>>>(src, dst, S, part, E, G, NB1);
    k_p2<<<G, 512, 0, stream>>>(part, S, rowptr, dinv, esorted, E, N, G, NB1);

    k_gemm1<<<(N + 15) / 16, 256, 0, stream>>>(x, W1, dinv, hp1h, N);
    k_agg1<<<(unsigned)(((size_t)N * 64 + 255) / 256), 256, 0, stream>>>(
        rowptr, esorted, (const __half2*)hp1h, dinv, b1, W2, hp2, N);
    k_agg2<<<(unsigned)(((size_t)N * 8 + 255) / 256), 256, 0, stream>>>(
        rowptr, esorted, hp2, dinv, b2, out, N);
}